// Round 1
// baseline (395.676 us; speedup 1.0000x reference)
//
#include <hip/hip_runtime.h>
#include <hip/hip_bf16.h>
#include <hip/hip_fp16.h>

#define N_NODES 100000
#define N_EDGES 1600000
#define C 128

typedef _Float16 half8 __attribute__((ext_vector_type(8)));
typedef _Float16 half4v __attribute__((ext_vector_type(4)));
typedef float f32x4 __attribute__((ext_vector_type(4)));

// ---------------- exclusive scan (3-kernel) ----------------
// scan_block now also folds the 4 replica degree arrays into a total degree
// and replaces degr[r][i] with the per-node exclusive scan over replicas
// (so fill_scatter can compute final slots without extra arrays).
__global__ __launch_bounds__(256) void scan_block(int* __restrict__ degr,
                                                  int* __restrict__ deg,
                                                  int* __restrict__ rowptr,
                                                  int* __restrict__ partial, int n) {
    __shared__ int s[256];
    int tid = threadIdx.x;
    int i = blockIdx.x * 256 + tid;
    int v = 0;
    if (i < n) {
        int d0 = degr[i];
        int d1 = degr[N_NODES + i];
        int d2 = degr[2 * N_NODES + i];
        int d3 = degr[3 * N_NODES + i];
        degr[i] = 0;
        degr[N_NODES + i] = d0;
        degr[2 * N_NODES + i] = d0 + d1;
        degr[3 * N_NODES + i] = d0 + d1 + d2;
        v = d0 + d1 + d2 + d3;
        deg[i] = v;
    }
    s[tid] = v;
    __syncthreads();
    for (int off = 1; off < 256; off <<= 1) {
        int t = (tid >= off) ? s[tid - off] : 0;
        __syncthreads();
        s[tid] += t;
        __syncthreads();
    }
    if (i < n) rowptr[i] = s[tid] - v;
    if (tid == 255) partial[blockIdx.x] = s[255];
}

__global__ __launch_bounds__(512) void scan_partial(int* __restrict__ partial, int n) {
    __shared__ int s[512];
    int tid = threadIdx.x;
    int v = (tid < n) ? partial[tid] : 0;
    s[tid] = v;
    __syncthreads();
    for (int off = 1; off < 512; off <<= 1) {
        int t = (tid >= off) ? s[tid - off] : 0;
        __syncthreads();
        s[tid] += t;
        __syncthreads();
    }
    if (tid < n) partial[tid] = s[tid] - v;
}

__global__ __launch_bounds__(256) void scan_finalize(int* __restrict__ rowptr,
                                                     const int* __restrict__ partial,
                                                     const int* __restrict__ deg,
                                                     float* __restrict__ isq,
                                                     int n, int E) {
    int i = blockIdx.x * 256 + threadIdx.x;
    if (i < n) {
        rowptr[i] += partial[blockIdx.x];
        isq[i] = rsqrtf((float)deg[i] + 1.0f);
    }
    if (i == 0) rowptr[n] = E;
}

// ---------------- CSR fill: atomic-free scatter ----------------
// pos = rowptr[dst] + (exclusive replica offset for this node) + local rank
__global__ __launch_bounds__(256) void fill_scatter(const int* __restrict__ src,
                                                    const int* __restrict__ dst,
                                                    const int* __restrict__ rank,
                                                    const int* __restrict__ rowptr,
                                                    const int* __restrict__ degr,
                                                    const float* __restrict__ isq,
                                                    long long* __restrict__ edges, int E) {
    int i = blockIdx.x * 256 + threadIdx.x;
    if (i < E) {
        int d = dst[i];
        int s = src[i];
        int pos = rowptr[d] + degr[(i & 3) * N_NODES + d] + rank[i];
        unsigned int cf = __float_as_uint(isq[s] * isq[d]);
        long long rec = (long long)(((unsigned long long)cf << 32) |
                                    (unsigned long long)(unsigned int)s);
        __builtin_nontemporal_store(rec, &edges[pos]);
    }
}

// ---------------- init: W pre-swizzle (blocks 0..15) + degr zero (rest) -----
__global__ __launch_bounds__(256) void init_kernel(const float* __restrict__ W1,
                                                   const float* __restrict__ W2,
                                                   _Float16* __restrict__ W1s,
                                                   _Float16* __restrict__ W2s,
                                                   int* __restrict__ degr, int n4) {
    if (blockIdx.x < 16) {
        int i = blockIdx.x * 256 + threadIdx.x;   // 0..4095
        int which = i >> 11;
        int u = i & 2047;
        int lane = u & 63, l = lane & 15, q = lane >> 4;
        int ct = u >> 6, c = ct >> 3, t = ct & 7;
        const float* Wsrc = which ? W2 : W1;
        _Float16* Dst = which ? W2s : W1s;
        half8 v;
#pragma unroll
        for (int j = 0; j < 8; j++)
            v[j] = (_Float16)Wsrc[(c * 32 + q * 8 + j) * C + t * 16 + l];
        *(half8*)(Dst + (size_t)u * 8) = v;
    } else {
        int i = (blockIdx.x - 16) * 256 + threadIdx.x;
        if (i < n4) degr[i] = 0;
    }
}

// ---------------- MFMA GEMM body (device fn, shared by 2 kernels) ----------
template <typename T>
__device__ __forceinline__ void gemm_body(const T* __restrict__ A,
                                          const _Float16* __restrict__ Wsw,
                                          _Float16* __restrict__ out, int n,
                                          int bid, int tid, _Float16* smem) {
    int lane = tid & 63;
    int w = tid >> 6;
    int m0 = bid * 64;

    // ---- stage A (64x128) to LDS fp16, granule g of row r at g^(r&15)
    if constexpr (sizeof(T) == 4) {
        const float4* A4 = (const float4*)A;
#pragma unroll
        for (int p = 0; p < 8; p++) {
            int idx = p * 256 + tid;
            int r = idx >> 5, f4 = idx & 31;
            int row = m0 + r; if (row >= n) row = n - 1;
            float4 v = A4[(size_t)row * 32 + f4];
            int kg = f4 >> 1, hi = f4 & 1;
            half4v hv = {(_Float16)v.x, (_Float16)v.y, (_Float16)v.z, (_Float16)v.w};
            *(half4v*)(smem + r * 128 + ((kg ^ (r & 15)) * 8) + hi * 4) = hv;
        }
    } else {
#pragma unroll
        for (int p = 0; p < 4; p++) {
            int idx = p * 256 + tid;
            int r = idx >> 4, kg = idx & 15;
            int row = m0 + r; if (row >= n) row = n - 1;
            half8 v = *(const half8*)(A + (size_t)row * C + kg * 8);
            *(half8*)(smem + r * 128 + ((kg ^ (r & 15)) * 8)) = v;
        }
    }
    __syncthreads();

    int l = lane & 15, q = lane >> 4;
    f32x4 acc[8] = {};

#pragma unroll
    for (int c = 0; c < 4; c++) {
        half8 af = *(const half8*)(smem + (w * 16 + l) * 128 + (((c * 4 + q) ^ l) * 8));
#pragma unroll
        for (int t = 0; t < 8; t++) {
            half8 bf = *(const half8*)(Wsw + (size_t)((c * 8 + t) * 64 + lane) * 8);
            acc[t] = __builtin_amdgcn_mfma_f32_16x16x32_f16(af, bf, acc[t], 0, 0, 0);
        }
    }

    __syncthreads();                       // all A reads done; reuse smem
    _Float16* cb = smem + w * 2176;        // [16][136] per wave
#pragma unroll
    for (int t = 0; t < 8; t++)
#pragma unroll
        for (int i = 0; i < 4; i++)        // C/D: col = t*16+l, row16 = q*4+i
            cb[(q * 4 + i) * 136 + t * 16 + l] = (_Float16)acc[t][i];
    __syncthreads();
#pragma unroll
    for (int i = 0; i < 4; i++) {
        int r16 = i * 4 + q;
        int row = m0 + w * 16 + r16;
        if (row < n)
            *(half8*)(out + (size_t)row * C + l * 8) =
                *(const half8*)(cb + r16 * 136 + l * 8);
    }
}

template <typename T>
__global__ __launch_bounds__(256) void gemm_mfma(const T* __restrict__ A,
                                                 const _Float16* __restrict__ Wsw,
                                                 _Float16* __restrict__ out, int n) {
    __shared__ _Float16 smem[8704];
    gemm_body<T>(A, Wsw, out, n, blockIdx.x, threadIdx.x, smem);
}

// ---------------- fused: gemm layer-1 (blocks < nbG) + deg_rank (rest) ------
// deg_rank: 4 edges/thread (int4 dst load), replica = edge&3 so the 4
// atomics hit 4 disjoint counter arrays -> 4x fewer RMWs per 64B line at the
// memory-side coherence point, and 4 independent atomics in flight per lane.
__global__ __launch_bounds__(256) void fused_deg_gemm(const float* __restrict__ x,
                                                      const _Float16* __restrict__ W1s,
                                                      _Float16* __restrict__ h16, int n,
                                                      const int* __restrict__ dst,
                                                      int* __restrict__ degr,
                                                      int* __restrict__ rank, int E,
                                                      int nbG) {
    __shared__ _Float16 smem[8704];
    if ((int)blockIdx.x < nbG) {
        gemm_body<float>(x, W1s, h16, n, blockIdx.x, threadIdx.x, smem);
    } else {
        int t = (blockIdx.x - nbG) * 256 + threadIdx.x;
        int base = t * 4;
        if (base < E) {   // E % 4 == 0, so all 4 lanes are in range
            int4 d4 = *(const int4*)(dst + base);
            int r0 = atomicAdd(&degr[0 * N_NODES + d4.x], 1);
            int r1 = atomicAdd(&degr[1 * N_NODES + d4.y], 1);
            int r2 = atomicAdd(&degr[2 * N_NODES + d4.z], 1);
            int r3 = atomicAdd(&degr[3 * N_NODES + d4.w], 1);
            int4 rr; rr.x = r0; rr.y = r1; rr.z = r2; rr.w = r3;
            *(int4*)(rank + base) = rr;
        }
    }
}

// ---------------- aggregation: one wave per dst node, fp16 h ----------------
template <bool RELU, typename OT>
__global__ __launch_bounds__(256) void aggregate(const _Float16* __restrict__ h,
                                                 const int* __restrict__ rowptr,
                                                 const long long* __restrict__ edges,
                                                 const float* __restrict__ isq,
                                                 const float* __restrict__ bias,
                                                 OT* __restrict__ out, int n) {
    int lane = threadIdx.x & 63;
    int wave = threadIdx.x >> 6;
    int node = blockIdx.x * 4 + wave;
    if (node >= n) return;

    int q   = lane >> 4;
    int l16 = lane & 15;
    int cb  = l16 * 8;

    int beg = rowptr[node];
    int end = rowptr[node + 1];

    float acc[8] = {};

    int j = beg + q;
    for (; j + 12 < end; j += 16) {
        unsigned long long e0 = (unsigned long long)edges[j];
        unsigned long long e1 = (unsigned long long)edges[j + 4];
        unsigned long long e2 = (unsigned long long)edges[j + 8];
        unsigned long long e3 = (unsigned long long)edges[j + 12];
        half8 h0 = *(const half8*)(h + (size_t)(unsigned int)e0 * C + cb);
        half8 h1 = *(const half8*)(h + (size_t)(unsigned int)e1 * C + cb);
        half8 h2 = *(const half8*)(h + (size_t)(unsigned int)e2 * C + cb);
        half8 h3 = *(const half8*)(h + (size_t)(unsigned int)e3 * C + cb);
        float c0 = __uint_as_float((unsigned int)(e0 >> 32));
        float c1 = __uint_as_float((unsigned int)(e1 >> 32));
        float c2 = __uint_as_float((unsigned int)(e2 >> 32));
        float c3 = __uint_as_float((unsigned int)(e3 >> 32));
#pragma unroll
        for (int k = 0; k < 8; k++) acc[k] += c0 * (float)h0[k];
#pragma unroll
        for (int k = 0; k < 8; k++) acc[k] += c1 * (float)h1[k];
#pragma unroll
        for (int k = 0; k < 8; k++) acc[k] += c2 * (float)h2[k];
#pragma unroll
        for (int k = 0; k < 8; k++) acc[k] += c3 * (float)h3[k];
    }
    for (; j < end; j += 4) {
        unsigned long long e = (unsigned long long)edges[j];
        half8 hv = *(const half8*)(h + (size_t)(unsigned int)e * C + cb);
        float cf = __uint_as_float((unsigned int)(e >> 32));
#pragma unroll
        for (int k = 0; k < 8; k++) acc[k] += cf * (float)hv[k];
    }

#pragma unroll
    for (int k = 0; k < 8; k++) {
        acc[k] += __shfl_xor(acc[k], 16, 64);
        acc[k] += __shfl_xor(acc[k], 32, 64);
    }

    if (q == 0) {
        float invd = isq[node];
        float sc = invd * invd;                     // self-loop coef = 1/deg
        half8 hd = *(const half8*)(h + (size_t)node * C + cb);
        float4 bv0 = *(const float4*)(bias + cb);
        float4 bv1 = *(const float4*)(bias + cb + 4);
        float bb[8] = {bv0.x, bv0.y, bv0.z, bv0.w, bv1.x, bv1.y, bv1.z, bv1.w};
#pragma unroll
        for (int k = 0; k < 8; k++) {
            acc[k] += sc * (float)hd[k] + bb[k];
            if (RELU) acc[k] = fmaxf(acc[k], 0.f);
        }
        if constexpr (sizeof(OT) == 2) {
            half8 o;
#pragma unroll
            for (int k = 0; k < 8; k++) o[k] = (_Float16)acc[k];
            *(half8*)((_Float16*)out + (size_t)node * C + cb) = o;
        } else {
            float4 o0 = {acc[0], acc[1], acc[2], acc[3]};
            float4 o1 = {acc[4], acc[5], acc[6], acc[7]};
            *(float4*)((float*)out + (size_t)node * C + cb) = o0;
            *(float4*)((float*)out + (size_t)node * C + cb + 4) = o1;
        }
    }
}

extern "C" void kernel_launch(void* const* d_in, const int* in_sizes, int n_in,
                              void* d_out, int out_size, void* d_ws, size_t ws_size,
                              hipStream_t stream) {
    const float* x  = (const float*)d_in[0];
    const int* ei   = (const int*)d_in[1];   // [2, E] int
    const float* W1 = (const float*)d_in[2];
    const float* b1 = (const float*)d_in[3];
    const float* W2 = (const float*)d_in[4];
    const float* b2 = (const float*)d_in[5];
    float* out = (float*)d_out;

    const int N = N_NODES, E = N_EDGES;
    const int* src = ei;
    const int* dst = ei + E;

    char* ws = (char*)d_ws;
    size_t off = 0;
    auto alloc = [&](size_t bytes) {
        size_t o = off;
        off = (off + bytes + 255) & ~(size_t)255;
        return o;
    };
    _Float16* h16   = (_Float16*)(ws + alloc((size_t)N * C * 2));  // gemm out / agg in
    _Float16* hB16  = (_Float16*)(ws + alloc((size_t)N * C * 2));  // agg1 out / gemm2 in
    _Float16* W1s   = (_Float16*)(ws + alloc((size_t)C * C * 2));
    _Float16* W2s   = (_Float16*)(ws + alloc((size_t)C * C * 2));
    int*      degr  = (int*)     (ws + alloc((size_t)4 * N * 4));  // 4 replica counters
    int*      deg   = (int*)     (ws + alloc((size_t)N * 4));      // summed degree
    float*    isq   = (float*)   (ws + alloc((size_t)N * 4));
    int*    rowptr  = (int*)     (ws + alloc((size_t)(N + 1) * 4));
    int*    rank    = (int*)     (ws + alloc((size_t)E * 4));
    int*    part    = (int*)     (ws + alloc((size_t)512 * 4));
    long long* edges = (long long*)(ws + alloc((size_t)E * 8));
    (void)ws_size; (void)n_in; (void)in_sizes; (void)out_size;

    const int nbN  = (N + 255) / 256;        // 391
    const int nbN4 = (4 * N + 255) / 256;    // 1563 (degr zeroing)
    const int nbE  = (E + 255) / 256;        // 6250
    const int nbE4 = (E / 4 + 255) / 256;    // 1563 (4 edges/thread)
    const int nbG  = (N + 63) / 64;          // 1563

    // 1: W swizzle + degr zeroing (one launch, independent halves)
    init_kernel<<<16 + nbN4, 256, 0, stream>>>(W1, W2, W1s, W2s, degr, 4 * N);

    // 2: gemm layer-1 co-scheduled with deg_rank (independent work)
    fused_deg_gemm<<<nbG + nbE4, 256, 0, stream>>>(x, W1s, h16, N, dst, degr, rank, E, nbG);

    // 3-5: CSR scan (scan_block also replica-scans degr in place)
    scan_block<<<nbN, 256, 0, stream>>>(degr, deg, rowptr, part, N);
    scan_partial<<<1, 512, 0, stream>>>(part, nbN);
    scan_finalize<<<nbN, 256, 0, stream>>>(rowptr, part, deg, isq, N, E);

    // 6: atomic-free CSR fill (pos = rowptr[dst] + replica offset + rank)
    fill_scatter<<<nbE, 256, 0, stream>>>(src, dst, rank, rowptr, degr, isq, edges, E);

    // 7: layer-1 aggregation (fp16 out)
    aggregate<true, _Float16><<<(N + 3) / 4, 256, 0, stream>>>(h16, rowptr, edges, isq, b1, hB16, N);

    // 8: layer-2 GEMM
    gemm_mfma<_Float16><<<nbG, 256, 0, stream>>>(hB16, W2s, h16, N);

    // 9: layer-2 aggregation (fp32 out)
    aggregate<false, float><<<(N + 3) / 4, 256, 0, stream>>>(h16, rowptr, edges, isq, b2, out, N);
}

// Round 2
// 338.993 us; speedup vs baseline: 1.1672x; 1.1672x over previous
//
#include <hip/hip_runtime.h>
#include <hip/hip_bf16.h>
#include <hip/hip_fp16.h>

#define N_NODES 100000
#define N_EDGES 1600000
#define C 128
#define NB 782              // node buckets of 128: ceil(100000/128)
#define NC 256              // edge chunks
#define EPC (N_EDGES / NC)  // 6250 edges per chunk (exact)

typedef _Float16 half8 __attribute__((ext_vector_type(8)));
typedef _Float16 half4v __attribute__((ext_vector_type(4)));
typedef float f32x4 __attribute__((ext_vector_type(4)));

// ---------------- init: W pre-swizzle (blocks 0..15) + bucket count (rest) --
// Count phase: per-chunk LDS histogram over 782 dst-buckets -> cnt[b][c].
// Zero global atomics (LDS only).
__global__ __launch_bounds__(256) void init_count(const float* __restrict__ W1,
                                                  const float* __restrict__ W2,
                                                  _Float16* __restrict__ W1s,
                                                  _Float16* __restrict__ W2s,
                                                  const int* __restrict__ dst,
                                                  int* __restrict__ cnt) {
    __shared__ int hist[NB];
    if (blockIdx.x < 16) {
        int i = blockIdx.x * 256 + threadIdx.x;   // 0..4095
        int which = i >> 11;
        int u = i & 2047;
        int lane = u & 63, l = lane & 15, q = lane >> 4;
        int ct = u >> 6, c = ct >> 3, t = ct & 7;
        const float* Wsrc = which ? W2 : W1;
        _Float16* Dst = which ? W2s : W1s;
        half8 v;
#pragma unroll
        for (int j = 0; j < 8; j++)
            v[j] = (_Float16)Wsrc[(c * 32 + q * 8 + j) * C + t * 16 + l];
        *(half8*)(Dst + (size_t)u * 8) = v;
    } else {
        int c = blockIdx.x - 16;                  // chunk 0..255
        int tid = threadIdx.x;
        for (int b = tid; b < NB; b += 256) hist[b] = 0;
        __syncthreads();
        int base = c * EPC;
        for (int i = tid; i < EPC; i += 256)
            atomicAdd(&hist[dst[base + i] >> 7], 1);
        __syncthreads();
        for (int b = tid; b < NB; b += 256) cnt[b * NC + c] = hist[b];
    }
}

// ---------------- generic exclusive scan over cnt (in place) ----------------
__global__ __launch_bounds__(256) void scan_block2(int* __restrict__ a,
                                                   int* __restrict__ partial, int n) {
    __shared__ int s[256];
    int tid = threadIdx.x;
    int i = blockIdx.x * 256 + tid;
    int v = (i < n) ? a[i] : 0;
    s[tid] = v;
    __syncthreads();
    for (int off = 1; off < 256; off <<= 1) {
        int t = (tid >= off) ? s[tid - off] : 0;
        __syncthreads();
        s[tid] += t;
        __syncthreads();
    }
    if (i < n) a[i] = s[tid] - v;                 // exclusive within block
    if (tid == 255) partial[blockIdx.x] = s[255];
}

__global__ __launch_bounds__(1024) void scan_partial_1024(int* __restrict__ partial, int n) {
    __shared__ int s[1024];
    int tid = threadIdx.x;
    int v = (tid < n) ? partial[tid] : 0;
    s[tid] = v;
    __syncthreads();
    for (int off = 1; off < 1024; off <<= 1) {
        int t = (tid >= off) ? s[tid - off] : 0;
        __syncthreads();
        s[tid] += t;
        __syncthreads();
    }
    if (tid < n) partial[tid] = s[tid] - v;
}

__global__ __launch_bounds__(256) void scan_add(int* __restrict__ a,
                                                const int* __restrict__ partial, int n) {
    int i = blockIdx.x * 256 + threadIdx.x;
    if (i < n) a[i] += partial[blockIdx.x];
}

// ---------------- MFMA GEMM body (device fn, shared by 2 kernels) ----------
template <typename T>
__device__ __forceinline__ void gemm_body(const T* __restrict__ A,
                                          const _Float16* __restrict__ Wsw,
                                          _Float16* __restrict__ out, int n,
                                          int bid, int tid, _Float16* smem) {
    int lane = tid & 63;
    int w = tid >> 6;
    int m0 = bid * 64;

    // ---- stage A (64x128) to LDS fp16, granule g of row r at g^(r&15)
    if constexpr (sizeof(T) == 4) {
        const float4* A4 = (const float4*)A;
#pragma unroll
        for (int p = 0; p < 8; p++) {
            int idx = p * 256 + tid;
            int r = idx >> 5, f4 = idx & 31;
            int row = m0 + r; if (row >= n) row = n - 1;
            float4 v = A4[(size_t)row * 32 + f4];
            int kg = f4 >> 1, hi = f4 & 1;
            half4v hv = {(_Float16)v.x, (_Float16)v.y, (_Float16)v.z, (_Float16)v.w};
            *(half4v*)(smem + r * 128 + ((kg ^ (r & 15)) * 8) + hi * 4) = hv;
        }
    } else {
#pragma unroll
        for (int p = 0; p < 4; p++) {
            int idx = p * 256 + tid;
            int r = idx >> 4, kg = idx & 15;
            int row = m0 + r; if (row >= n) row = n - 1;
            half8 v = *(const half8*)(A + (size_t)row * C + kg * 8);
            *(half8*)(smem + r * 128 + ((kg ^ (r & 15)) * 8)) = v;
        }
    }
    __syncthreads();

    int l = lane & 15, q = lane >> 4;
    f32x4 acc[8] = {};

#pragma unroll
    for (int c = 0; c < 4; c++) {
        half8 af = *(const half8*)(smem + (w * 16 + l) * 128 + (((c * 4 + q) ^ l) * 8));
#pragma unroll
        for (int t = 0; t < 8; t++) {
            half8 bf = *(const half8*)(Wsw + (size_t)((c * 8 + t) * 64 + lane) * 8);
            acc[t] = __builtin_amdgcn_mfma_f32_16x16x32_f16(af, bf, acc[t], 0, 0, 0);
        }
    }

    __syncthreads();                       // all A reads done; reuse smem
    _Float16* cb = smem + w * 2176;        // [16][136] per wave
#pragma unroll
    for (int t = 0; t < 8; t++)
#pragma unroll
        for (int i = 0; i < 4; i++)        // C/D: col = t*16+l, row16 = q*4+i
            cb[(q * 4 + i) * 136 + t * 16 + l] = (_Float16)acc[t][i];
    __syncthreads();
#pragma unroll
    for (int i = 0; i < 4; i++) {
        int r16 = i * 4 + q;
        int row = m0 + w * 16 + r16;
        if (row < n)
            *(half8*)(out + (size_t)row * C + l * 8) =
                *(const half8*)(cb + r16 * 136 + l * 8);
    }
}

template <typename T>
__global__ __launch_bounds__(256) void gemm_mfma(const T* __restrict__ A,
                                                 const _Float16* __restrict__ Wsw,
                                                 _Float16* __restrict__ out, int n) {
    __shared__ _Float16 smem[8704];
    gemm_body<T>(A, Wsw, out, n, blockIdx.x, threadIdx.x, smem);
}

// ---------------- fused: gemm layer-1 (blocks < nbG) + bucket scatter -------
// Scatter: each chunk places its edges into bucket-sorted order via LDS
// cursors (off[b] preloaded from scanned cnt). Zero global atomics.
__global__ __launch_bounds__(256) void fused_gemm_scatter(const float* __restrict__ x,
                                                          const _Float16* __restrict__ W1s,
                                                          _Float16* __restrict__ h16, int n,
                                                          const int* __restrict__ src,
                                                          const int* __restrict__ dst,
                                                          const int* __restrict__ S,
                                                          long long* __restrict__ bsorted,
                                                          int nbG) {
    __shared__ _Float16 smem[8704];
    if ((int)blockIdx.x < nbG) {
        gemm_body<float>(x, W1s, h16, n, blockIdx.x, threadIdx.x, smem);
    } else {
        int c = blockIdx.x - nbG;
        int tid = threadIdx.x;
        int* off = (int*)smem;                       // 782 ints, aliases gemm smem
        for (int b = tid; b < NB; b += 256) off[b] = S[b * NC + c];
        __syncthreads();
        int base = c * EPC;
        for (int i = tid; i < EPC; i += 256) {
            int s = src[base + i];
            int d = dst[base + i];
            int p = atomicAdd(&off[d >> 7], 1);      // LDS atomic
            bsorted[p] = ((long long)(unsigned long long)(unsigned int)d << 32) |
                         (unsigned int)s;
        }
    }
}

// ---------------- node sort: one block per bucket ---------------------------
// Bucket-sorted records -> node-sorted; emits rowptr, isq, (isq_dst, src).
__global__ __launch_bounds__(256) void node_sort(const long long* __restrict__ bsorted,
                                                 const int* __restrict__ S,
                                                 long long* __restrict__ final2,
                                                 int* __restrict__ rowptr,
                                                 float* __restrict__ isq) {
    __shared__ int hist[128];
    __shared__ int sc[128];
    __shared__ int off2[128];
    __shared__ float iqb[128];
    int b = blockIdx.x, tid = threadIdx.x;
    int beg = S[b * NC];
    int end = (b == NB - 1) ? N_EDGES : S[(b + 1) * NC];
    if (tid < 128) hist[tid] = 0;
    __syncthreads();
    for (int i = beg + tid; i < end; i += 256) {
        int d = (int)((unsigned long long)bsorted[i] >> 32);
        atomicAdd(&hist[d & 127], 1);
    }
    __syncthreads();
    if (tid < 128) sc[tid] = hist[tid];
    __syncthreads();
    for (int off = 1; off < 128; off <<= 1) {
        int t = 0;
        if (tid < 128 && tid >= off) t = sc[tid - off];
        __syncthreads();
        if (tid < 128) sc[tid] += t;
        __syncthreads();
    }
    if (tid < 128) {
        int node = b * 128 + tid;
        int deg = hist[tid];
        int start = beg + sc[tid] - deg;             // exclusive scan
        off2[tid] = start;
        if (node < N_NODES) {
            rowptr[node] = start;
            float iq = rsqrtf((float)deg + 1.0f);    // +1: self-loop
            isq[node] = iq;
            iqb[tid] = iq;
        }
    }
    if (b == 0 && tid == 0) rowptr[N_NODES] = N_EDGES;
    __syncthreads();
    for (int i = beg + tid; i < end; i += 256) {
        long long rec = bsorted[i];
        int d = (int)((unsigned long long)rec >> 32);
        int li = d & 127;
        int p = atomicAdd(&off2[li], 1);             // LDS atomic
        final2[p] = ((long long)(unsigned long long)__float_as_uint(iqb[li]) << 32) |
                    (unsigned int)(rec & 0xffffffffLL);
    }
}

// ---------------- coef fill: (isq_dst, src) -> (coef, src) -----------------
__global__ __launch_bounds__(256) void coef_fill(const long long* __restrict__ final2,
                                                 const float* __restrict__ isq,
                                                 long long* __restrict__ edges, int E) {
    int i = blockIdx.x * 256 + threadIdx.x;
    if (i < E) {
        long long rec = final2[i];
        int s = (int)(rec & 0xffffffffLL);
        float iqd = __uint_as_float((unsigned int)((unsigned long long)rec >> 32));
        float cf = isq[s] * iqd;
        long long orec = ((long long)(unsigned long long)__float_as_uint(cf) << 32) |
                         (unsigned int)s;
        __builtin_nontemporal_store(orec, &edges[i]);
    }
}

// ---------------- aggregation: one wave per dst node, fp16 h ----------------
template <bool RELU, typename OT>
__global__ __launch_bounds__(256) void aggregate(const _Float16* __restrict__ h,
                                                 const int* __restrict__ rowptr,
                                                 const long long* __restrict__ edges,
                                                 const float* __restrict__ isq,
                                                 const float* __restrict__ bias,
                                                 OT* __restrict__ out, int n) {
    int lane = threadIdx.x & 63;
    int wave = threadIdx.x >> 6;
    int node = blockIdx.x * 4 + wave;
    if (node >= n) return;

    int q   = lane >> 4;
    int l16 = lane & 15;
    int cb  = l16 * 8;

    int beg = rowptr[node];
    int end = rowptr[node + 1];

    float acc[8] = {};

    int j = beg + q;
    for (; j + 12 < end; j += 16) {
        unsigned long long e0 = (unsigned long long)edges[j];
        unsigned long long e1 = (unsigned long long)edges[j + 4];
        unsigned long long e2 = (unsigned long long)edges[j + 8];
        unsigned long long e3 = (unsigned long long)edges[j + 12];
        half8 h0 = *(const half8*)(h + (size_t)(unsigned int)e0 * C + cb);
        half8 h1 = *(const half8*)(h + (size_t)(unsigned int)e1 * C + cb);
        half8 h2 = *(const half8*)(h + (size_t)(unsigned int)e2 * C + cb);
        half8 h3 = *(const half8*)(h + (size_t)(unsigned int)e3 * C + cb);
        float c0 = __uint_as_float((unsigned int)(e0 >> 32));
        float c1 = __uint_as_float((unsigned int)(e1 >> 32));
        float c2 = __uint_as_float((unsigned int)(e2 >> 32));
        float c3 = __uint_as_float((unsigned int)(e3 >> 32));
#pragma unroll
        for (int k = 0; k < 8; k++) acc[k] += c0 * (float)h0[k];
#pragma unroll
        for (int k = 0; k < 8; k++) acc[k] += c1 * (float)h1[k];
#pragma unroll
        for (int k = 0; k < 8; k++) acc[k] += c2 * (float)h2[k];
#pragma unroll
        for (int k = 0; k < 8; k++) acc[k] += c3 * (float)h3[k];
    }
    for (; j < end; j += 4) {
        unsigned long long e = (unsigned long long)edges[j];
        half8 hv = *(const half8*)(h + (size_t)(unsigned int)e * C + cb);
        float cf = __uint_as_float((unsigned int)(e >> 32));
#pragma unroll
        for (int k = 0; k < 8; k++) acc[k] += cf * (float)hv[k];
    }

#pragma unroll
    for (int k = 0; k < 8; k++) {
        acc[k] += __shfl_xor(acc[k], 16, 64);
        acc[k] += __shfl_xor(acc[k], 32, 64);
    }

    if (q == 0) {
        float invd = isq[node];
        float sc = invd * invd;                     // self-loop coef = 1/deg
        half8 hd = *(const half8*)(h + (size_t)node * C + cb);
        float4 bv0 = *(const float4*)(bias + cb);
        float4 bv1 = *(const float4*)(bias + cb + 4);
        float bb[8] = {bv0.x, bv0.y, bv0.z, bv0.w, bv1.x, bv1.y, bv1.z, bv1.w};
#pragma unroll
        for (int k = 0; k < 8; k++) {
            acc[k] += sc * (float)hd[k] + bb[k];
            if (RELU) acc[k] = fmaxf(acc[k], 0.f);
        }
        if constexpr (sizeof(OT) == 2) {
            half8 o;
#pragma unroll
            for (int k = 0; k < 8; k++) o[k] = (_Float16)acc[k];
            *(half8*)((_Float16*)out + (size_t)node * C + cb) = o;
        } else {
            float4 o0 = {acc[0], acc[1], acc[2], acc[3]};
            float4 o1 = {acc[4], acc[5], acc[6], acc[7]};
            *(float4*)((float*)out + (size_t)node * C + cb) = o0;
            *(float4*)((float*)out + (size_t)node * C + cb + 4) = o1;
        }
    }
}

extern "C" void kernel_launch(void* const* d_in, const int* in_sizes, int n_in,
                              void* d_out, int out_size, void* d_ws, size_t ws_size,
                              hipStream_t stream) {
    const float* x  = (const float*)d_in[0];
    const int* ei   = (const int*)d_in[1];   // [2, E] int
    const float* W1 = (const float*)d_in[2];
    const float* b1 = (const float*)d_in[3];
    const float* W2 = (const float*)d_in[4];
    const float* b2 = (const float*)d_in[5];
    float* out = (float*)d_out;

    const int N = N_NODES, E = N_EDGES;
    const int* src = ei;
    const int* dst = ei + E;

    char* ws = (char*)d_ws;
    size_t off = 0;
    auto alloc = [&](size_t bytes) {
        size_t o = off;
        off = (off + bytes + 255) & ~(size_t)255;
        return o;
    };
    _Float16* h16   = (_Float16*)(ws + alloc((size_t)N * C * 2));  // gemm out / agg in
    _Float16* hB16  = (_Float16*)(ws + alloc((size_t)N * C * 2));  // agg1 out / gemm2 in
    _Float16* W1s   = (_Float16*)(ws + alloc((size_t)C * C * 2));
    _Float16* W2s   = (_Float16*)(ws + alloc((size_t)C * C * 2));
    int*      cnt   = (int*)     (ws + alloc((size_t)NB * NC * 4)); // count/scan table
    int*      part  = (int*)     (ws + alloc((size_t)1024 * 4));
    long long* ebuf1 = (long long*)(ws + alloc((size_t)E * 8));    // bsorted, then final edges
    long long* ebuf2 = (long long*)(ws + alloc((size_t)E * 8));    // (isq_dst, src)
    int*    rowptr  = (int*)     (ws + alloc((size_t)(N + 1) * 4));
    float*    isq   = (float*)   (ws + alloc((size_t)N * 4));
    (void)ws_size; (void)n_in; (void)in_sizes; (void)out_size;

    const int nbG = (N + 63) / 64;     // 1563
    const int nS  = NB * NC;           // 200192
    const int nbS = nS / 256;          // 782 (exact)
    const int nbE = (E + 255) / 256;   // 6250

    // 1: W swizzle + per-chunk bucket count (LDS histograms, no global atomics)
    init_count<<<16 + NC, 256, 0, stream>>>(W1, W2, W1s, W2s, dst, cnt);

    // 2-4: exclusive scan of cnt[bucket][chunk]
    scan_block2<<<nbS, 256, 0, stream>>>(cnt, part, nS);
    scan_partial_1024<<<1, 1024, 0, stream>>>(part, nbS);
    scan_add<<<nbS, 256, 0, stream>>>(cnt, part, nS);

    // 5: gemm layer-1 co-scheduled with bucket scatter (LDS cursors)
    fused_gemm_scatter<<<nbG + NC, 256, 0, stream>>>(x, W1s, h16, N, src, dst, cnt,
                                                     ebuf1, nbG);

    // 6: per-bucket node sort -> rowptr, isq, (isq_dst, src)
    node_sort<<<NB, 256, 0, stream>>>(ebuf1, cnt, ebuf2, rowptr, isq);

    // 7: coefficient fill -> (coef, src), overwrites ebuf1
    coef_fill<<<nbE, 256, 0, stream>>>(ebuf2, isq, ebuf1, E);

    // 8: layer-1 aggregation (fp16 out)
    aggregate<true, _Float16><<<(N + 3) / 4, 256, 0, stream>>>(h16, rowptr, ebuf1, isq, b1, hB16, N);

    // 9: layer-2 GEMM
    gemm_mfma<_Float16><<<nbG, 256, 0, stream>>>(hB16, W2s, h16, N);

    // 10: layer-2 aggregation (fp32 out)
    aggregate<false, float><<<(N + 3) / 4, 256, 0, stream>>>(h16, rowptr, ebuf1, isq, b2, out, N);
}